// Round 14
// baseline (57.327 us; speedup 1.0000x reference)
//
#include <hip/hip_runtime.h>
#include <math.h>

#define NT  4096   // B*T tokens
#define DD  128
#define EE  256

// ---- K1: fused router: logits + top2 + select. 256 blocks x 16 tokens. -----
// Wg streamed once per 16 tokens (32 MB total, was 64). 16 acc chains/thread.
__global__ __launch_bounds__(256) void router_kernel(
    const float* __restrict__ x, const float* __restrict__ Wg,
    const float* __restrict__ bg, float2* __restrict__ ww,
    int2* __restrict__ sel)
{
    const int bid = blockIdx.x;
    const int tid = threadIdx.x;
    const int t0  = bid * 16;

    __shared__ float xt[DD][16];  // 8 KB, transposed token rows
    __shared__ float lg[16][EE];  // 16 KB, logits

    // stage 16 rows (r13-expert-validated pattern): q = token, part = 8-float chunk
    {
        const int q = tid >> 4, part = tid & 15;
        const float4* xr = reinterpret_cast<const float4*>(
            x + (size_t)(t0 + q) * DD) + part * 2;
        const float4 u0 = xr[0], u1 = xr[1];
        xt[part * 8 + 0][q] = u0.x;  xt[part * 8 + 1][q] = u0.y;
        xt[part * 8 + 2][q] = u0.z;  xt[part * 8 + 3][q] = u0.w;
        xt[part * 8 + 4][q] = u1.x;  xt[part * 8 + 5][q] = u1.y;
        xt[part * 8 + 6][q] = u1.z;  xt[part * 8 + 7][q] = u1.w;
    }
    __syncthreads();

    // logits: thread e accumulates 16 token-logits, Wg streamed coalesced
    {
        const int e = tid;
        const float be = bg[e];
        float acc[16];
        #pragma unroll
        for (int i = 0; i < 16; ++i) acc[i] = be;
        #pragma unroll 4
        for (int d = 0; d < DD; ++d) {
            const float w = Wg[(size_t)d * EE + e];
            const float4 x0 = *reinterpret_cast<const float4*>(&xt[d][0]);
            const float4 x1 = *reinterpret_cast<const float4*>(&xt[d][4]);
            const float4 x2 = *reinterpret_cast<const float4*>(&xt[d][8]);
            const float4 x3 = *reinterpret_cast<const float4*>(&xt[d][12]);
            acc[0]  = fmaf(x0.x, w, acc[0]);   acc[1]  = fmaf(x0.y, w, acc[1]);
            acc[2]  = fmaf(x0.z, w, acc[2]);   acc[3]  = fmaf(x0.w, w, acc[3]);
            acc[4]  = fmaf(x1.x, w, acc[4]);   acc[5]  = fmaf(x1.y, w, acc[5]);
            acc[6]  = fmaf(x1.z, w, acc[6]);   acc[7]  = fmaf(x1.w, w, acc[7]);
            acc[8]  = fmaf(x2.x, w, acc[8]);   acc[9]  = fmaf(x2.y, w, acc[9]);
            acc[10] = fmaf(x2.z, w, acc[10]);  acc[11] = fmaf(x2.w, w, acc[11]);
            acc[12] = fmaf(x3.x, w, acc[12]);  acc[13] = fmaf(x3.y, w, acc[13]);
            acc[14] = fmaf(x3.z, w, acc[14]);  acc[15] = fmaf(x3.w, w, acc[15]);
        }
        #pragma unroll
        for (int tk = 0; tk < 16; ++tk) lg[tk][e] = acc[tk];
    }
    __syncthreads();

    // top2 per wave: 4 waves x 4 tokens (proven reduce body)
    const int lane = tid & 63;
    const int wv   = tid >> 6;
    #pragma unroll
    for (int rep = 0; rep < 4; ++rep) {
        const int tk = wv * 4 + rep;
        const int t  = t0 + tk;
        const float4 lv = *reinterpret_cast<const float4*>(&lg[tk][lane * 4]);
        float v[4] = {lv.x, lv.y, lv.z, lv.w};

        float m = v[0]; int mi = lane * 4;
        #pragma unroll
        for (int j = 1; j < 4; ++j)
            if (v[j] > m) { m = v[j]; mi = lane * 4 + j; }
        #pragma unroll
        for (int s = 32; s; s >>= 1) {
            const float om = __shfl_xor(m, s);
            const int   oi = __shfl_xor(mi, s);
            if (om > m || (om == m && oi < mi)) { m = om; mi = oi; }
        }

        float ssum = 0.0f;
        #pragma unroll
        for (int j = 0; j < 4; ++j) ssum += __expf(v[j] - m);
        #pragma unroll
        for (int s = 32; s; s >>= 1) ssum += __shfl_xor(ssum, s);

        float m2 = -INFINITY; int mi2 = 0;
        #pragma unroll
        for (int j = 0; j < 4; ++j) {
            const int ei = lane * 4 + j;
            if (ei != mi && v[j] > m2) { m2 = v[j]; mi2 = ei; }
        }
        #pragma unroll
        for (int s = 32; s; s >>= 1) {
            const float om = __shfl_xor(m2, s);
            const int   oi = __shfl_xor(mi2, s);
            if (om > m2 || (om == m2 && oi < mi2)) { m2 = om; mi2 = oi; }
        }

        if (lane == 0) {
            const float p1 = 1.0f / ssum;
            const float p2 = __expf(m2 - m) / ssum;
            const float den = p1 + p2 + 1e-6f;
            ww[t]  = make_float2(p1 / den, p2 / den);
            sel[t] = make_int2(mi, mi2);
        }
    }
}

// ---- K2: expert matvecs (r11 verbatim — the 49.6us champion config) --------
__global__ __launch_bounds__(128) void expert_kernel(
    const float* __restrict__ x, const float* __restrict__ ew,
    const int2* __restrict__ sel, float* __restrict__ ybuf)
{
    const int wg = (blockIdx.x & 7) * 128 + (blockIdx.x >> 3);
    const int e  = wg >> 2;
    const int c  = wg & 3;
    const int tid = threadIdx.x;

    __shared__ float xt[DD][8];   // 4 KB
    __shared__ int   lst[128];
    __shared__ int   lcnt;
    if (tid == 0) lcnt = 0;
    __syncthreads();

    const int tbase = c * 1024;
    #pragma unroll
    for (int it = 0; it < 8; ++it) {
        const int tok = tbase + it * 128 + tid;
        const int2 s = sel[tok];
        if (s.x == e) { const int p = atomicAdd(&lcnt, 1); if (p < 128) lst[p] = 2 * tok; }
        if (s.y == e) { const int p = atomicAdd(&lcnt, 1); if (p < 128) lst[p] = 2 * tok + 1; }
    }
    __syncthreads();
    int n = lcnt;
    if (n > 128) n = 128;
    if (n == 0) return;

    const int o = tid;
    const float* W = ew + (size_t)e * DD * DD;

    for (int base = 0; base < n; base += 8) {
        {
            const int q = tid >> 4, part = tid & 15;
            if (base + q < n) {
                const int fi = lst[base + q];
                const float4* xr = reinterpret_cast<const float4*>(
                    x + (size_t)(fi >> 1) * DD) + part * 2;
                const float4 u0 = xr[0], u1 = xr[1];
                xt[part * 8 + 0][q] = u0.x;  xt[part * 8 + 1][q] = u0.y;
                xt[part * 8 + 2][q] = u0.z;  xt[part * 8 + 3][q] = u0.w;
                xt[part * 8 + 4][q] = u1.x;  xt[part * 8 + 5][q] = u1.y;
                xt[part * 8 + 6][q] = u1.z;  xt[part * 8 + 7][q] = u1.w;
            }
        }
        __syncthreads();

        float a0 = 0.f, a1 = 0.f, a2 = 0.f, a3 = 0.f;
        float a4 = 0.f, a5 = 0.f, a6 = 0.f, a7 = 0.f;
        #pragma unroll 8
        for (int d = 0; d < DD; ++d) {
            const float w = W[(size_t)d * DD + o];
            const float4 xa = *reinterpret_cast<const float4*>(&xt[d][0]);
            const float4 xb = *reinterpret_cast<const float4*>(&xt[d][4]);
            a0 = fmaf(xa.x, w, a0);  a1 = fmaf(xa.y, w, a1);
            a2 = fmaf(xa.z, w, a2);  a3 = fmaf(xa.w, w, a3);
            a4 = fmaf(xb.x, w, a4);  a5 = fmaf(xb.y, w, a5);
            a6 = fmaf(xb.z, w, a6);  a7 = fmaf(xb.w, w, a7);
        }

        if (base + 0 < n) ybuf[(size_t)lst[base + 0] * DD + o] = a0;
        if (base + 1 < n) ybuf[(size_t)lst[base + 1] * DD + o] = a1;
        if (base + 2 < n) ybuf[(size_t)lst[base + 2] * DD + o] = a2;
        if (base + 3 < n) ybuf[(size_t)lst[base + 3] * DD + o] = a3;
        if (base + 4 < n) ybuf[(size_t)lst[base + 4] * DD + o] = a4;
        if (base + 5 < n) ybuf[(size_t)lst[base + 5] * DD + o] = a5;
        if (base + 6 < n) ybuf[(size_t)lst[base + 6] * DD + o] = a6;
        if (base + 7 < n) ybuf[(size_t)lst[base + 7] * DD + o] = a7;
        __syncthreads();
    }
}

// ---- K3: mixed + SwiGLU + consensus. 256 blocks x 16 tokens. ---------------
// w1/w2 streamed once per 16 tokens (32 MB total, was 64). 16 chains/thread.
__global__ __launch_bounds__(256) void swiglu_kernel(
    const float* __restrict__ ybuf, const float2* __restrict__ ww,
    const float* __restrict__ w1, const float* __restrict__ b1,
    const float* __restrict__ w2, const float* __restrict__ b2,
    float* __restrict__ out_avg, float* __restrict__ out_cons)
{
    const int tid = threadIdx.x;
    const int t0  = blockIdx.x * 16;

    __shared__ float mt[DD][16];     // mixed, transposed       (8 KB)
    __shared__ float gh[2][16][DD];  // g (0) / h (1) per token (16 KB)

    // ---- Phase A: mixed -> mt[d][q] (q = token, part = 8-float chunk) ----
    {
        const int q = tid >> 4, part = tid & 15;
        const int t = t0 + q;
        const float2 w = ww[t];
        const float4* ar = reinterpret_cast<const float4*>(
            ybuf + (size_t)(2 * t) * DD) + part * 2;
        const float4* br = reinterpret_cast<const float4*>(
            ybuf + (size_t)(2 * t + 1) * DD) + part * 2;
        const float4 a0 = ar[0], a1 = ar[1];
        const float4 b0 = br[0], b1v = br[1];
        mt[part * 8 + 0][q] = w.x * a0.x + w.y * b0.x;
        mt[part * 8 + 1][q] = w.x * a0.y + w.y * b0.y;
        mt[part * 8 + 2][q] = w.x * a0.z + w.y * b0.z;
        mt[part * 8 + 3][q] = w.x * a0.w + w.y * b0.w;
        mt[part * 8 + 4][q] = w.x * a1.x + w.y * b1v.x;
        mt[part * 8 + 5][q] = w.x * a1.y + w.y * b1v.y;
        mt[part * 8 + 6][q] = w.x * a1.z + w.y * b1v.z;
        mt[part * 8 + 7][q] = w.x * a1.w + w.y * b1v.w;
    }
    __syncthreads();

    // ---- Phase B: g/h GEMV, streamed weights, 16 chains ----
    {
        const int o = tid & 127, h = tid >> 7;
        const float* Wc = h ? w2 : w1;
        const float bias = h ? b2[o] : b1[o];
        float acc[16];
        #pragma unroll
        for (int i = 0; i < 16; ++i) acc[i] = bias;
        #pragma unroll 4
        for (int d = 0; d < DD; ++d) {
            const float w = Wc[(size_t)d * DD + o];
            const float4 x0 = *reinterpret_cast<const float4*>(&mt[d][0]);
            const float4 x1 = *reinterpret_cast<const float4*>(&mt[d][4]);
            const float4 x2 = *reinterpret_cast<const float4*>(&mt[d][8]);
            const float4 x3 = *reinterpret_cast<const float4*>(&mt[d][12]);
            acc[0]  = fmaf(x0.x, w, acc[0]);   acc[1]  = fmaf(x0.y, w, acc[1]);
            acc[2]  = fmaf(x0.z, w, acc[2]);   acc[3]  = fmaf(x0.w, w, acc[3]);
            acc[4]  = fmaf(x1.x, w, acc[4]);   acc[5]  = fmaf(x1.y, w, acc[5]);
            acc[6]  = fmaf(x1.z, w, acc[6]);   acc[7]  = fmaf(x1.w, w, acc[7]);
            acc[8]  = fmaf(x2.x, w, acc[8]);   acc[9]  = fmaf(x2.y, w, acc[9]);
            acc[10] = fmaf(x2.z, w, acc[10]);  acc[11] = fmaf(x2.w, w, acc[11]);
            acc[12] = fmaf(x3.x, w, acc[12]);  acc[13] = fmaf(x3.y, w, acc[13]);
            acc[14] = fmaf(x3.z, w, acc[14]);  acc[15] = fmaf(x3.w, w, acc[15]);
        }
        #pragma unroll
        for (int tk = 0; tk < 16; ++tk) gh[h][tk][o] = acc[tk];
    }
    __syncthreads();

    // ---- Phase C: wavg + variance epilogue; 16 threads per token ----
    {
        const int q = tid >> 4, part = tid & 15;
        const int t = t0 + q;
        const float2 w = ww[t];
        const float4* ar = reinterpret_cast<const float4*>(
            ybuf + (size_t)(2 * t) * DD) + part * 2;
        const float4* br = reinterpret_cast<const float4*>(
            ybuf + (size_t)(2 * t + 1) * DD) + part * 2;
        const float4 gv0 = *reinterpret_cast<const float4*>(&gh[0][q][part * 8]);
        const float4 gv1 = *reinterpret_cast<const float4*>(&gh[0][q][part * 8 + 4]);
        const float4 hv0 = *reinterpret_cast<const float4*>(&gh[1][q][part * 8]);
        const float4 hv1 = *reinterpret_cast<const float4*>(&gh[1][q][part * 8 + 4]);

        float v = 0.0f;
        float4 r0, r1;
        {
            const float4 a = ar[0], b = br[0];
            {
                const float g = gv0.x, sig = 1.0f / (1.0f + __expf(-g));
                r0.x = g * sig * hv0.x;
                const float da = a.x - r0.x, db = b.x - r0.x;
                v += w.x * da * da + w.y * db * db;
            }
            {
                const float g = gv0.y, sig = 1.0f / (1.0f + __expf(-g));
                r0.y = g * sig * hv0.y;
                const float da = a.y - r0.y, db = b.y - r0.y;
                v += w.x * da * da + w.y * db * db;
            }
            {
                const float g = gv0.z, sig = 1.0f / (1.0f + __expf(-g));
                r0.z = g * sig * hv0.z;
                const float da = a.z - r0.z, db = b.z - r0.z;
                v += w.x * da * da + w.y * db * db;
            }
            {
                const float g = gv0.w, sig = 1.0f / (1.0f + __expf(-g));
                r0.w = g * sig * hv0.w;
                const float da = a.w - r0.w, db = b.w - r0.w;
                v += w.x * da * da + w.y * db * db;
            }
        }
        {
            const float4 a = ar[1], b = br[1];
            {
                const float g = gv1.x, sig = 1.0f / (1.0f + __expf(-g));
                r1.x = g * sig * hv1.x;
                const float da = a.x - r1.x, db = b.x - r1.x;
                v += w.x * da * da + w.y * db * db;
            }
            {
                const float g = gv1.y, sig = 1.0f / (1.0f + __expf(-g));
                r1.y = g * sig * hv1.y;
                const float da = a.y - r1.y, db = b.y - r1.y;
                v += w.x * da * da + w.y * db * db;
            }
            {
                const float g = gv1.z, sig = 1.0f / (1.0f + __expf(-g));
                r1.z = g * sig * hv1.z;
                const float da = a.z - r1.z, db = b.z - r1.z;
                v += w.x * da * da + w.y * db * db;
            }
            {
                const float g = gv1.w, sig = 1.0f / (1.0f + __expf(-g));
                r1.w = g * sig * hv1.w;
                const float da = a.w - r1.w, db = b.w - r1.w;
                v += w.x * da * da + w.y * db * db;
            }
        }
        float4* outr = reinterpret_cast<float4*>(out_avg + (size_t)t * DD) + part * 2;
        outr[0] = r0;  outr[1] = r1;

        // reduce over the 16 threads of token q (contiguous lanes in a wave)
        v += __shfl_down(v, 8);
        v += __shfl_down(v, 4);
        v += __shfl_down(v, 2);
        v += __shfl_down(v, 1);
        if (part == 0) out_cons[t] = __expf(-v * (1.0f / DD));
    }
}

extern "C" void kernel_launch(void* const* d_in, const int* in_sizes, int n_in,
                              void* d_out, int out_size, void* d_ws, size_t ws_size,
                              hipStream_t stream) {
    const float* x   = (const float*)d_in[0];
    const float* Wg  = (const float*)d_in[1];
    const float* bg  = (const float*)d_in[2];
    const float* ew  = (const float*)d_in[3];
    const float* w1  = (const float*)d_in[4];
    const float* b1  = (const float*)d_in[5];
    const float* w2  = (const float*)d_in[6];
    const float* b2  = (const float*)d_in[7];

    float* out_avg  = (float*)d_out;              // [NT, D]
    float* out_cons = out_avg + (size_t)NT * DD;  // [NT]

    // ws layout: ybuf 4MB | ww 32KB | sel 32KB
    char* ws = (char*)d_ws;
    float*  ybuf = (float*)ws;                               // [NT*2, DD]
    float2* wwp  = (float2*)(ws + 4 * 1024 * 1024);
    int2*   selp = (int2*)  (ws + 4 * 1024 * 1024 + 32 * 1024);

    router_kernel<<<NT / 16, 256, 0, stream>>>(x, Wg, bg, wwp, selp);
    expert_kernel<<<EE * 4, 128, 0, stream>>>(x, ew, selp, ybuf);
    swiglu_kernel<<<NT / 16, 256, 0, stream>>>(ybuf, wwp, w1, b1, w2, b2,
                                               out_avg, out_cons);
}

// Round 15
// 48.750 us; speedup vs baseline: 1.1759x; 1.1759x over previous
//
#include <hip/hip_runtime.h>
#include <math.h>

#define NT  4096   // B*T tokens
#define DD  128
#define EE  256

// ---- K1: fused router: logits + top2 + select (r11 verbatim, champion) -----
__global__ __launch_bounds__(256) void router_kernel(
    const float* __restrict__ x, const float* __restrict__ Wg,
    const float* __restrict__ bg, float2* __restrict__ ww,
    int2* __restrict__ sel)
{
    const int bid = blockIdx.x;
    const int tid = threadIdx.x;
    const int t0  = bid * 8;

    __shared__ float xt[DD][8];   // 4 KB, transposed token rows
    __shared__ float lg[8][EE];   // 8 KB, logits

    {
        const int q = tid >> 5, part = tid & 31;
        const float4 v = *(reinterpret_cast<const float4*>(
            x + (size_t)(t0 + q) * DD) + part);
        xt[part * 4 + 0][q] = v.x;
        xt[part * 4 + 1][q] = v.y;
        xt[part * 4 + 2][q] = v.z;
        xt[part * 4 + 3][q] = v.w;
    }
    __syncthreads();

    {
        const int e = tid;
        const float be = bg[e];
        float a0 = be, a1 = be, a2 = be, a3 = be;
        float a4 = be, a5 = be, a6 = be, a7 = be;
        #pragma unroll 8
        for (int d = 0; d < DD; ++d) {
            const float w = Wg[(size_t)d * EE + e];       // coalesced stream
            const float4 xa = *reinterpret_cast<const float4*>(&xt[d][0]);
            const float4 xb = *reinterpret_cast<const float4*>(&xt[d][4]);
            a0 = fmaf(xa.x, w, a0);  a1 = fmaf(xa.y, w, a1);
            a2 = fmaf(xa.z, w, a2);  a3 = fmaf(xa.w, w, a3);
            a4 = fmaf(xb.x, w, a4);  a5 = fmaf(xb.y, w, a5);
            a6 = fmaf(xb.z, w, a6);  a7 = fmaf(xb.w, w, a7);
        }
        lg[0][e] = a0;  lg[1][e] = a1;  lg[2][e] = a2;  lg[3][e] = a3;
        lg[4][e] = a4;  lg[5][e] = a5;  lg[6][e] = a6;  lg[7][e] = a7;
    }
    __syncthreads();

    const int lane = tid & 63;
    const int wv   = tid >> 6;
    #pragma unroll
    for (int rep = 0; rep < 2; ++rep) {
        const int tk = wv * 2 + rep;
        const int t  = t0 + tk;
        const float4 lv = *reinterpret_cast<const float4*>(&lg[tk][lane * 4]);
        float v[4] = {lv.x, lv.y, lv.z, lv.w};

        float m = v[0]; int mi = lane * 4;
        #pragma unroll
        for (int j = 1; j < 4; ++j)
            if (v[j] > m) { m = v[j]; mi = lane * 4 + j; }
        #pragma unroll
        for (int s = 32; s; s >>= 1) {
            const float om = __shfl_xor(m, s);
            const int   oi = __shfl_xor(mi, s);
            if (om > m || (om == m && oi < mi)) { m = om; mi = oi; }
        }

        float ssum = 0.0f;
        #pragma unroll
        for (int j = 0; j < 4; ++j) ssum += __expf(v[j] - m);
        #pragma unroll
        for (int s = 32; s; s >>= 1) ssum += __shfl_xor(ssum, s);

        float m2 = -INFINITY; int mi2 = 0;
        #pragma unroll
        for (int j = 0; j < 4; ++j) {
            const int ei = lane * 4 + j;
            if (ei != mi && v[j] > m2) { m2 = v[j]; mi2 = ei; }
        }
        #pragma unroll
        for (int s = 32; s; s >>= 1) {
            const float om = __shfl_xor(m2, s);
            const int   oi = __shfl_xor(mi2, s);
            if (om > m2 || (om == m2 && oi < mi2)) { m2 = om; mi2 = oi; }
        }

        if (lane == 0) {
            const float p1 = 1.0f / ssum;
            const float p2 = __expf(m2 - m) / ssum;
            const float den = p1 + p2 + 1e-6f;
            ww[t]  = make_float2(p1 / den, p2 / den);
            sel[t] = make_int2(mi, mi2);
        }
    }
}

// ---- K2: expert matvecs (r11 verbatim, champion) ---------------------------
__global__ __launch_bounds__(128) void expert_kernel(
    const float* __restrict__ x, const float* __restrict__ ew,
    const int2* __restrict__ sel, float* __restrict__ ybuf)
{
    const int wg = (blockIdx.x & 7) * 128 + (blockIdx.x >> 3);
    const int e  = wg >> 2;
    const int c  = wg & 3;
    const int tid = threadIdx.x;

    __shared__ float xt[DD][8];   // 4 KB
    __shared__ int   lst[128];
    __shared__ int   lcnt;
    if (tid == 0) lcnt = 0;
    __syncthreads();

    const int tbase = c * 1024;
    #pragma unroll
    for (int it = 0; it < 8; ++it) {
        const int tok = tbase + it * 128 + tid;
        const int2 s = sel[tok];
        if (s.x == e) { const int p = atomicAdd(&lcnt, 1); if (p < 128) lst[p] = 2 * tok; }
        if (s.y == e) { const int p = atomicAdd(&lcnt, 1); if (p < 128) lst[p] = 2 * tok + 1; }
    }
    __syncthreads();
    int n = lcnt;
    if (n > 128) n = 128;
    if (n == 0) return;

    const int o = tid;
    const float* W = ew + (size_t)e * DD * DD;

    for (int base = 0; base < n; base += 8) {
        {
            const int q = tid >> 4, part = tid & 15;
            if (base + q < n) {
                const int fi = lst[base + q];
                const float4* xr = reinterpret_cast<const float4*>(
                    x + (size_t)(fi >> 1) * DD) + part * 2;
                const float4 u0 = xr[0], u1 = xr[1];
                xt[part * 8 + 0][q] = u0.x;  xt[part * 8 + 1][q] = u0.y;
                xt[part * 8 + 2][q] = u0.z;  xt[part * 8 + 3][q] = u0.w;
                xt[part * 8 + 4][q] = u1.x;  xt[part * 8 + 5][q] = u1.y;
                xt[part * 8 + 6][q] = u1.z;  xt[part * 8 + 7][q] = u1.w;
            }
        }
        __syncthreads();

        float a0 = 0.f, a1 = 0.f, a2 = 0.f, a3 = 0.f;
        float a4 = 0.f, a5 = 0.f, a6 = 0.f, a7 = 0.f;
        #pragma unroll 8
        for (int d = 0; d < DD; ++d) {
            const float w = W[(size_t)d * DD + o];        // coalesced stream
            const float4 xa = *reinterpret_cast<const float4*>(&xt[d][0]);
            const float4 xb = *reinterpret_cast<const float4*>(&xt[d][4]);
            a0 = fmaf(xa.x, w, a0);  a1 = fmaf(xa.y, w, a1);
            a2 = fmaf(xa.z, w, a2);  a3 = fmaf(xa.w, w, a3);
            a4 = fmaf(xb.x, w, a4);  a5 = fmaf(xb.y, w, a5);
            a6 = fmaf(xb.z, w, a6);  a7 = fmaf(xb.w, w, a7);
        }

        if (base + 0 < n) ybuf[(size_t)lst[base + 0] * DD + o] = a0;
        if (base + 1 < n) ybuf[(size_t)lst[base + 1] * DD + o] = a1;
        if (base + 2 < n) ybuf[(size_t)lst[base + 2] * DD + o] = a2;
        if (base + 3 < n) ybuf[(size_t)lst[base + 3] * DD + o] = a3;
        if (base + 4 < n) ybuf[(size_t)lst[base + 4] * DD + o] = a4;
        if (base + 5 < n) ybuf[(size_t)lst[base + 5] * DD + o] = a5;
        if (base + 6 < n) ybuf[(size_t)lst[base + 6] * DD + o] = a6;
        if (base + 7 < n) ybuf[(size_t)lst[base + 7] * DD + o] = a7;
        __syncthreads();
    }
}

// ---- K3: swiglu (r11 structure + register-carry of ya/yb/w across phases) --
__global__ __launch_bounds__(256) void swiglu_kernel(
    const float* __restrict__ ybuf, const float2* __restrict__ ww,
    const float* __restrict__ w1, const float* __restrict__ b1,
    const float* __restrict__ w2, const float* __restrict__ b2,
    float* __restrict__ out_avg, float* __restrict__ out_cons)
{
    const int tid = threadIdx.x;
    const int t0  = blockIdx.x * 8;

    __shared__ float mt[DD][8];      // mixed, transposed      (4 KB)
    __shared__ float gh[2][8][DD];   // g (0) and h (1) per token (8 KB)

    // Phase A and Phase C use the SAME (q,part) mapping -> carry a, b, w
    // in registers across the barriers (saves 4 MB of L2 re-reads).
    const int q = tid >> 5, part = tid & 31;
    const int t = t0 + q;
    const float2 w = ww[t];
    const float4 a = *(reinterpret_cast<const float4*>(
        ybuf + (size_t)(2 * t) * DD) + part);
    const float4 b = *(reinterpret_cast<const float4*>(
        ybuf + (size_t)(2 * t + 1) * DD) + part);

    // ---- Phase A: mixed -> mt[d][q] ----
    mt[part * 4 + 0][q] = w.x * a.x + w.y * b.x;
    mt[part * 4 + 1][q] = w.x * a.y + w.y * b.y;
    mt[part * 4 + 2][q] = w.x * a.z + w.y * b.z;
    mt[part * 4 + 3][q] = w.x * a.w + w.y * b.w;
    __syncthreads();

    // ---- Phase B: g/h GEMV, streamed weights, 8 independent chains ----
    {
        const int o = tid & 127, h = tid >> 7;
        const float* Wc = h ? w2 : w1;
        const float bias = h ? b2[o] : b1[o];
        float a0 = bias, a1 = bias, a2 = bias, a3 = bias;
        float a4 = bias, a5 = bias, a6 = bias, a7 = bias;
        #pragma unroll 8
        for (int d = 0; d < DD; ++d) {
            const float wv = Wc[(size_t)d * DD + o];      // coalesced stream
            const float4 xa = *reinterpret_cast<const float4*>(&mt[d][0]);
            const float4 xb = *reinterpret_cast<const float4*>(&mt[d][4]);
            a0 = fmaf(xa.x, wv, a0);  a1 = fmaf(xa.y, wv, a1);
            a2 = fmaf(xa.z, wv, a2);  a3 = fmaf(xa.w, wv, a3);
            a4 = fmaf(xb.x, wv, a4);  a5 = fmaf(xb.y, wv, a5);
            a6 = fmaf(xb.z, wv, a6);  a7 = fmaf(xb.w, wv, a7);
        }
        gh[h][0][o] = a0;  gh[h][1][o] = a1;  gh[h][2][o] = a2;  gh[h][3][o] = a3;
        gh[h][4][o] = a4;  gh[h][5][o] = a5;  gh[h][6][o] = a6;  gh[h][7][o] = a7;
    }
    __syncthreads();

    // ---- Phase C: wavg + variance epilogue (a, b, w carried in registers) --
    {
        const float4 gv = *reinterpret_cast<const float4*>(&gh[0][q][part * 4]);
        const float4 hv = *reinterpret_cast<const float4*>(&gh[1][q][part * 4]);

        float4 r; float v = 0.0f;
        {
            const float g = gv.x, sig = 1.0f / (1.0f + __expf(-g));
            r.x = g * sig * hv.x;
            const float da = a.x - r.x, db = b.x - r.x;
            v += w.x * da * da + w.y * db * db;
        }
        {
            const float g = gv.y, sig = 1.0f / (1.0f + __expf(-g));
            r.y = g * sig * hv.y;
            const float da = a.y - r.y, db = b.y - r.y;
            v += w.x * da * da + w.y * db * db;
        }
        {
            const float g = gv.z, sig = 1.0f / (1.0f + __expf(-g));
            r.z = g * sig * hv.z;
            const float da = a.z - r.z, db = b.z - r.z;
            v += w.x * da * da + w.y * db * db;
        }
        {
            const float g = gv.w, sig = 1.0f / (1.0f + __expf(-g));
            r.w = g * sig * hv.w;
            const float da = a.w - r.w, db = b.w - r.w;
            v += w.x * da * da + w.y * db * db;
        }
        *(reinterpret_cast<float4*>(out_avg + (size_t)t * DD) + part) = r;

        #pragma unroll
        for (int s = 16; s; s >>= 1) v += __shfl_down(v, s);
        if (part == 0) out_cons[t] = __expf(-v * (1.0f / DD));
    }
}

extern "C" void kernel_launch(void* const* d_in, const int* in_sizes, int n_in,
                              void* d_out, int out_size, void* d_ws, size_t ws_size,
                              hipStream_t stream) {
    const float* x   = (const float*)d_in[0];
    const float* Wg  = (const float*)d_in[1];
    const float* bg  = (const float*)d_in[2];
    const float* ew  = (const float*)d_in[3];
    const float* w1  = (const float*)d_in[4];
    const float* b1  = (const float*)d_in[5];
    const float* w2  = (const float*)d_in[6];
    const float* b2  = (const float*)d_in[7];

    float* out_avg  = (float*)d_out;              // [NT, D]
    float* out_cons = out_avg + (size_t)NT * DD;  // [NT]

    // ws layout: ybuf 4MB | ww 32KB | sel 32KB
    char* ws = (char*)d_ws;
    float*  ybuf = (float*)ws;                               // [NT*2, DD]
    float2* wwp  = (float2*)(ws + 4 * 1024 * 1024);
    int2*   selp = (int2*)  (ws + 4 * 1024 * 1024 + 32 * 1024);

    router_kernel<<<NT / 8, 256, 0, stream>>>(x, Wg, bg, wwp, selp);
    expert_kernel<<<EE * 4, 128, 0, stream>>>(x, ew, selp, ybuf);
    swiglu_kernel<<<NT / 8, 256, 0, stream>>>(ybuf, wwp, w1, b1, w2, b2,
                                              out_avg, out_cons);
}